// Round 3
// baseline (312.603 us; speedup 1.0000x reference)
//
#include <hip/hip_runtime.h>
#include <stdint.h>

#define DEV __device__ __forceinline__

// ---------------------------------------------------------------- helpers
DEV uint32_t rotl32(uint32_t x, int r) { return (x << r) | (x >> (32 - r)); }

// JAX Threefry-2x32 with key = (0, 42)  (jax.random.key(42))
DEV void threefry_0_42(uint32_t x0, uint32_t x1, uint32_t& o0, uint32_t& o1) {
  const uint32_t ks0 = 0u, ks1 = 42u, ks2 = 0x1BD11BDAu ^ 42u;
  x0 += ks0; x1 += ks1;
#define TFR(r) { x0 += x1; x1 = rotl32(x1, (r)); x1 ^= x0; }
  TFR(13) TFR(15) TFR(26) TFR(6)  x0 += ks1; x1 += ks2 + 1u;
  TFR(17) TFR(29) TFR(16) TFR(24) x0 += ks2; x1 += ks0 + 2u;
  TFR(13) TFR(15) TFR(26) TFR(6)  x0 += ks0; x1 += ks1 + 3u;
  TFR(17) TFR(29) TFR(16) TFR(24) x0 += ks1; x1 += ks2 + 4u;
  TFR(13) TFR(15) TFR(26) TFR(6)  x0 += ks2; x1 += ks0 + 5u;
#undef TFR
  o0 = x0; o1 = x1;
}

DEV float wredmax(float v) {
#pragma unroll
  for (int off = 32; off > 0; off >>= 1) v = fmaxf(v, __shfl_xor(v, off));
  return v;
}
DEV float wredsum(float v) {
#pragma unroll
  for (int off = 32; off > 0; off >>= 1) v += __shfl_xor(v, off);
  return v;
}

// 16 FMAs of the 4x4 micro tile
#define MICRO_FMA(a, b, acc)                                            \
  acc[0][0] = fmaf(a.x, b.x, acc[0][0]); acc[0][1] = fmaf(a.x, b.y, acc[0][1]); \
  acc[0][2] = fmaf(a.x, b.z, acc[0][2]); acc[0][3] = fmaf(a.x, b.w, acc[0][3]); \
  acc[1][0] = fmaf(a.y, b.x, acc[1][0]); acc[1][1] = fmaf(a.y, b.y, acc[1][1]); \
  acc[1][2] = fmaf(a.y, b.z, acc[1][2]); acc[1][3] = fmaf(a.y, b.w, acc[1][3]); \
  acc[2][0] = fmaf(a.z, b.x, acc[2][0]); acc[2][1] = fmaf(a.z, b.y, acc[2][1]); \
  acc[2][2] = fmaf(a.z, b.z, acc[2][2]); acc[2][3] = fmaf(a.z, b.w, acc[2][3]); \
  acc[3][0] = fmaf(a.w, b.x, acc[3][0]); acc[3][1] = fmaf(a.w, b.y, acc[3][1]); \
  acc[3][2] = fmaf(a.w, b.z, acc[3][2]); acc[3][3] = fmaf(a.w, b.w, acc[3][3]);

// ---------------------------------------------------------------- generic fp32 GEMM
// C[M x N] = A[M x K] @ B[K x N]; tile 64x64, BK=16, 256 threads, 4x4/thread.
__global__ __launch_bounds__(256) void gemm_f32(const float* __restrict__ A, int lda,
                                                const float* __restrict__ B, int ldb,
                                                float* __restrict__ C, int ldc, int K) {
  __shared__ float As[16][68];
  __shared__ float Bs[16][64];
  const int tid = threadIdx.x;
  const int tx = tid & 15, ty = tid >> 4;
  const int rt = blockIdx.x, ct = blockIdx.y;
  const int arow = tid >> 2, ak0 = (tid & 3) * 4;
  const int bk = tid >> 4, bc0 = (tid & 15) * 4;
  const float* Ap = A + (long)(rt * 64 + arow) * lda + ak0;
  const float* Bp = B + (long)bk * ldb + ct * 64 + bc0;
  float acc[4][4] = {};
  for (int kt = 0; kt < K; kt += 16) {
    float4 a4 = *(const float4*)(Ap + kt);
    float4 b4 = *(const float4*)(Bp + (long)kt * ldb);
    As[ak0 + 0][arow] = a4.x; As[ak0 + 1][arow] = a4.y;
    As[ak0 + 2][arow] = a4.z; As[ak0 + 3][arow] = a4.w;
    *(float4*)&Bs[bk][bc0] = b4;
    __syncthreads();
#pragma unroll
    for (int k = 0; k < 16; ++k) {
      float4 a = *(const float4*)&As[k][ty * 4];
      float4 b = *(const float4*)&Bs[k][tx * 4];
      MICRO_FMA(a, b, acc)
    }
    __syncthreads();
  }
#pragma unroll
  for (int i = 0; i < 4; ++i) {
    float4 o; o.x = acc[i][0]; o.y = acc[i][1]; o.z = acc[i][2]; o.w = acc[i][3];
    *(float4*)(C + (long)(rt * 64 + ty * 4 + i) * ldc + ct * 64 + tx * 4) = o;
  }
}

// ---------------------------------------------------------------- scores + softmax + gumbel
// One block per (n,t). Produces alpha[n,t,:] and y_align[n,t,:].
__global__ __launch_bounds__(256) void scores_kernel(const float* __restrict__ uh,
                                                     const float* __restrict__ wq,
                                                     const float* __restrict__ v,
                                                     float* __restrict__ alpha_g,
                                                     float* __restrict__ y_g) {
  const int tid = threadIdx.x;
  const int nt = blockIdx.x;           // n*64 + t
  const int n = nt >> 6;
  __shared__ float uhs[64][65];
  __shared__ float sc[1024];
  __shared__ float psum[4][64];
  __shared__ float red[4];
  const int sl = tid & 63, dq = tid >> 6;

  float wqr[16], vr[16];
#pragma unroll
  for (int j = 0; j < 16; ++j) {
    wqr[j] = wq[nt * 64 + dq * 16 + j];
    vr[j]  = v[dq * 16 + j];
  }
  const float* uhn = uh + (long)n * 65536;

  for (int t = 0; t < 16; ++t) {
#pragma unroll
    for (int i = 0; i < 4; ++i) {
      int fi = (i * 256 + tid) * 4;
      float4 val = *(const float4*)(uhn + t * 4096 + fi);
      int r = fi >> 6, d = fi & 63;
      uhs[r][d] = val.x; uhs[r][d + 1] = val.y; uhs[r][d + 2] = val.z; uhs[r][d + 3] = val.w;
    }
    __syncthreads();
    float acc = 0.f;
#pragma unroll
    for (int j = 0; j < 16; ++j) {
      float x = uhs[sl][dq * 16 + j] + wqr[j];
      acc = fmaf(tanhf(x), vr[j], acc);
    }
    psum[dq][sl] = acc;
    __syncthreads();
    if (dq == 0) sc[t * 64 + sl] = psum[0][sl] + psum[1][sl] + psum[2][sl] + psum[3][sl];
    __syncthreads();
  }

  // ---- log_softmax over S=1024 ----
  float lsc[4];
#pragma unroll
  for (int i = 0; i < 4; ++i) lsc[i] = sc[tid + 256 * i];
  const int wv = tid >> 6, ln = tid & 63;

  float m = fmaxf(fmaxf(lsc[0], lsc[1]), fmaxf(lsc[2], lsc[3]));
  m = wredmax(m);
  if (ln == 0) red[wv] = m;
  __syncthreads();
  m = fmaxf(fmaxf(red[0], red[1]), fmaxf(red[2], red[3]));
  __syncthreads();
  float ss = 0.f;
#pragma unroll
  for (int i = 0; i < 4; ++i) ss += expf(lsc[i] - m);
  ss = wredsum(ss);
  if (ln == 0) red[wv] = ss;
  __syncthreads();
  ss = red[0] + red[1] + red[2] + red[3];
  const float logl = logf(ss);
  __syncthreads();

  // ---- alpha + gumbel noise (JAX PARTITIONABLE threefry, key=(0,42)) ----
  // jax_threefry_partitionable=True (default since ~0.4.36): element j uses
  // 64-bit counter j -> pair (hi=0, lo=j); 32-bit output = o0 ^ o1.
  float ys[4];
#pragma unroll
  for (int i = 0; i < 4; ++i) {
    int s = tid + 256 * i;
    float la = lsc[i] - m - logl;
    alpha_g[(long)nt * 1024 + s] = expf(la);
    uint32_t j = (uint32_t)nt * 1024u + (uint32_t)s;  // flat [N,T,S] index, < 2^20
    uint32_t o0, o1;
    threefry_0_42(0u, j, o0, o1);
    uint32_t bits = o0 ^ o1;
    float u = __uint_as_float((bits >> 9) | 0x3f800000u) - 1.0f;
    float g = -logf(-logf(u + 1e-20f) + 1e-20f);
    ys[i] = (la + g) * 2.0f;                           // /TEMPERATURE (0.5)
  }

  // ---- softmax over ys ----
  float m2 = fmaxf(fmaxf(ys[0], ys[1]), fmaxf(ys[2], ys[3]));
  m2 = wredmax(m2);
  if (ln == 0) red[wv] = m2;
  __syncthreads();
  m2 = fmaxf(fmaxf(red[0], red[1]), fmaxf(red[2], red[3]));
  __syncthreads();
  float s2 = 0.f;
  float ye[4];
#pragma unroll
  for (int i = 0; i < 4; ++i) { ye[i] = expf(ys[i] - m2); s2 += ye[i]; }
  s2 = wredsum(s2);
  if (ln == 0) red[wv] = s2;
  __syncthreads();
  s2 = red[0] + red[1] + red[2] + red[3];
  const float rinv = 1.0f / s2;
#pragma unroll
  for (int i = 0; i < 4; ++i) y_g[(long)nt * 1024 + tid + 256 * i] = ye[i] * rinv;
}

// ---------------------------------------------------------------- context GEMM (batched over n)
// grid (2, 8, 16): variant vt in {0:alpha,1:y}, col tile ct, batch n.
__global__ __launch_bounds__(256) void gemm_ctx(const float* __restrict__ alpha,
                                                const float* __restrict__ yal,
                                                const float* __restrict__ mb,
                                                float* __restrict__ ctx) {
  __shared__ float As[16][68];
  __shared__ float Bs[16][64];
  const int tid = threadIdx.x;
  const int tx = tid & 15, ty = tid >> 4;
  const int vt = blockIdx.x, ct = blockIdx.y, n = blockIdx.z;
  const int arow = tid >> 2, ak0 = (tid & 3) * 4;
  const int bk = tid >> 4, bc0 = (tid & 15) * 4;
  const float* Abase = (vt == 0 ? alpha : yal) + (long)n * 65536;
  const float* Ap = Abase + (long)arow * 1024 + ak0;
  const float* Bp = mb + (long)n * 524288 + (long)bk * 512 + ct * 64 + bc0;
  float acc[4][4] = {};
  for (int kt = 0; kt < 1024; kt += 16) {
    float4 a4 = *(const float4*)(Ap + kt);
    float4 b4 = *(const float4*)(Bp + (long)kt * 512);
    As[ak0 + 0][arow] = a4.x; As[ak0 + 1][arow] = a4.y;
    As[ak0 + 2][arow] = a4.z; As[ak0 + 3][arow] = a4.w;
    *(float4*)&Bs[bk][bc0] = b4;
    __syncthreads();
#pragma unroll
    for (int k = 0; k < 16; ++k) {
      float4 a = *(const float4*)&As[k][ty * 4];
      float4 b = *(const float4*)&Bs[k][tx * 4];
      MICRO_FMA(a, b, acc)
    }
    __syncthreads();
  }
#pragma unroll
  for (int i = 0; i < 4; ++i) {
    float4 o; o.x = acc[i][0]; o.y = acc[i][1]; o.z = acc[i][2]; o.w = acc[i][3];
    *(float4*)(ctx + (long)(vt * 1024 + n * 64 + ty * 4 + i) * 512 + ct * 64 + tx * 4) = o;
  }
}

// ---------------------------------------------------------------- output GEMM + bias + tanh
__global__ __launch_bounds__(256) void gemm_out(const float* __restrict__ input,
                                                const float* __restrict__ ctx,
                                                const float* __restrict__ Wout,
                                                const float* __restrict__ bout,
                                                float* __restrict__ out) {
  __shared__ float As[16][68];
  __shared__ float Bs[16][64];
  const int tid = threadIdx.x;
  const int tx = tid & 15, ty = tid >> 4;
  const int rt = blockIdx.x, ct = blockIdx.y;
  const int arow = tid >> 2, ak0 = (tid & 3) * 4;
  const int bk = tid >> 4, bc0 = (tid & 15) * 4;
  const int rg = rt * 64 + arow;
  const int v = rg >> 10, nt = rg & 1023;
  const float* Ain  = input + (long)nt * 512;
  const float* Actx = ctx + (long)(v * 1024 + nt) * 512 - 512;
  const float* Bp = Wout + (long)bk * 512 + ct * 64 + bc0;
  float acc[4][4] = {};
  for (int kt = 0; kt < 1024; kt += 16) {
    const float* Ap = (kt < 512) ? Ain : Actx;   // tiles never straddle the 512 boundary
    float4 a4 = *(const float4*)(Ap + kt + ak0);
    float4 b4 = *(const float4*)(Bp + (long)kt * 512);
    As[ak0 + 0][arow] = a4.x; As[ak0 + 1][arow] = a4.y;
    As[ak0 + 2][arow] = a4.z; As[ak0 + 3][arow] = a4.w;
    *(float4*)&Bs[bk][bc0] = b4;
    __syncthreads();
#pragma unroll
    for (int k = 0; k < 16; ++k) {
      float4 a = *(const float4*)&As[k][ty * 4];
      float4 b = *(const float4*)&Bs[k][tx * 4];
      MICRO_FMA(a, b, acc)
    }
    __syncthreads();
  }
  float4 bo = *(const float4*)(bout + ct * 64 + tx * 4);
  float bb[4] = {bo.x, bo.y, bo.z, bo.w};
#pragma unroll
  for (int i = 0; i < 4; ++i) {
    int rgo = rt * 64 + ty * 4 + i;
    float4 o;
    o.x = tanhf(acc[i][0] + bb[0]);
    o.y = tanhf(acc[i][1] + bb[1]);
    o.z = tanhf(acc[i][2] + bb[2]);
    o.w = tanhf(acc[i][3] + bb[3]);
    *(float4*)(out + (long)rgo * 512 + ct * 64 + tx * 4) = o;
  }
}

// ---------------------------------------------------------------- launch
// Workspace: 12.25 MiB, all in d_ws (no d_out aliasing):
//   uh    [0       , 1048576)   floats   (dead after scores -> reused as ctx)
//   wq    [1048576 , 1114112)
//   alpha [1114112 , 2162688)
//   yal   [2162688 , 3211264)
extern "C" void kernel_launch(void* const* d_in, const int* in_sizes, int n_in,
                              void* d_out, int out_size, void* d_ws, size_t ws_size,
                              hipStream_t stream) {
  const float* input = (const float*)d_in[0];   // [16,64,512]
  const float* mb    = (const float*)d_in[1];   // [16,1024,512]
  const float* W_q   = (const float*)d_in[2];   // [512,64]
  const float* W_ctx = (const float*)d_in[3];   // [512,64]
  const float* v     = (const float*)d_in[4];   // [64]
  const float* W_out = (const float*)d_in[5];   // [1024,512]
  const float* b_out = (const float*)d_in[6];   // [512]
  float* out = (float*)d_out;                   // [2,16,64,512]
  float* ws = (float*)d_ws;

  float* uh    = ws;                  // [16,1024,64]
  float* wq    = ws + 1048576;        // [1024,64]
  float* alpha = ws + 1114112;        // [1024,1024]
  float* yal   = ws + 2162688;        // [1024,1024]
  float* ctx   = uh;                  // [2,1024,512] aliases dead uh

  gemm_f32<<<dim3(256, 1), 256, 0, stream>>>(mb, 512, W_ctx, 64, uh, 64, 512);
  gemm_f32<<<dim3(16, 1), 256, 0, stream>>>(input, 512, W_q, 64, wq, 64, 512);
  scores_kernel<<<1024, 256, 0, stream>>>(uh, wq, v, alpha, yal);
  gemm_ctx<<<dim3(2, 8, 16), 256, 0, stream>>>(alpha, yal, mb, ctx);
  gemm_out<<<dim3(32, 8), 256, 0, stream>>>(input, ctx, W_out, b_out, out);
}